// Round 16
// baseline (370.983 us; speedup 1.0000x reference)
//
#include <hip/hip_runtime.h>

typedef __bf16 bf16x8 __attribute__((ext_vector_type(8)));
typedef float  f32x4  __attribute__((ext_vector_type(4)));
typedef float  f32x16 __attribute__((ext_vector_type(16)));
typedef unsigned short u16;
typedef unsigned short u16x8 __attribute__((ext_vector_type(8)));

__device__ __forceinline__ u16 f2bf(float f) {
  unsigned u = __builtin_bit_cast(unsigned, f);
  u += 0x7fffu + ((u >> 16) & 1u);           // round-to-nearest-even
  return (u16)(u >> 16);
}
__device__ __forceinline__ float bf2f(u16 h) {
  return __builtin_bit_cast(float, (unsigned)h << 16);
}

using gvoid = __attribute__((address_space(1))) void;
using svoid = __attribute__((address_space(3))) void;
__device__ __forceinline__ void load_lds16(const void* g, void* s) {
  __builtin_amdgcn_global_load_lds((const gvoid*)g, (svoid*)s, 16, 0, 0);
}

// ---------- prep: transpose+cvt F (z<8, fused passthrough) | weights f32->bf16 (z>=8) ----
__global__ void prep(const float* __restrict__ Fr, const float* __restrict__ Fi,
                     u16* __restrict__ FTr, u16* __restrict__ FTi,
                     float* __restrict__ Or, float* __restrict__ Oi,
                     const float* __restrict__ s0, const float* __restrict__ s1,
                     const float* __restrict__ s2, const float* __restrict__ s3,
                     const float* __restrict__ s4, const float* __restrict__ s5,
                     u16* __restrict__ Wall) {
  const int tx = threadIdx.x, ty = threadIdx.y;
  const int t2 = ty * 32 + tx;
  if (blockIdx.z >= 8) {
    const int gi = (blockIdx.z - 8) * 1024 + blockIdx.y * 32 + blockIdx.x;
    const int chunk = gi >> 12;                         // 6 chunks x 4096 blocks
    const int i = (gi & 4095) * 256 + t2;               // quad index in chunk
    const float* src;
    switch (chunk) {
      case 0: src = s0; break; case 1: src = s1; break; case 2: src = s2; break;
      case 3: src = s3; break; case 4: src = s4; break; default: src = s5; break;
    }
    float4 v = ((const float4*)src)[i];
    ushort4 o;
    o.x = f2bf(v.x); o.y = f2bf(v.y); o.z = f2bf(v.z); o.w = f2bf(v.w);
    ((ushort4*)(Wall + (long)chunk * 4194304))[i] = o;
    return;
  }
  __shared__ float tile[64][33];
  const int b = blockIdx.z & 3;
  const bool ind = (blockIdx.z >= 4);
  const float* F = ind ? Fi : Fr;
  u16* FT = ind ? FTi : FTr;
  float* O = ind ? Oi : Or;
  const int n0 = blockIdx.x * 32, c0 = blockIdx.y * 64;
  const long boff = (long)b * 2048 * 1024;
  const float* Fb = F + boff;
  float* Ob = O + boff;
  u16* FTb = FT + (long)b * 1024 * 2048;
#pragma unroll
  for (int i = 0; i < 8; ++i) {
    const long idx = (long)(c0 + ty + i * 8) * 1024 + n0 + tx;
    float v = Fb[idx];
    tile[ty + i * 8][tx] = v;
    Ob[idx] = v;                                  // identity passthrough (full lines)
  }
  __syncthreads();
  const int q = t2 & 7, r = t2 >> 3;
  u16x8 o8;
#pragma unroll
  for (int k = 0; k < 8; ++k) o8[k] = f2bf(tile[8 * q + k][r]);
  *(u16x8*)(FTb + (long)(n0 + r) * 2048 + c0 + 8 * q) = o8;
}

// ================= 256x256 4-phase bf16 GEMM, 32x32x16 MFMA core =================
// R16: identical schedule/staging/swizzle/traffic to R15; MFMA shape swapped to
// 32x32x16 (m119: 8.07 cyc/32k FLOP vs 9.7 for 2x 16x16x32 -> -17% matrix cycles;
// same LDS fragment bytes, same 128-reg acc). Fragment layouts: A row=l&31,
// k-octet=l>>5 (row=lane%M, kblk=lane/M rule); C/D col=lane&31,
// row=(reg&3)+8*(reg>>2)+4*(lane>>5) [guide m74/m101, HW-verified].
// Epilogue: 4 chunks of [64][256] via LDS-bounce -> full-line 16 B/lane stores.

#define BAR_ do { asm volatile("" ::: "memory"); __builtin_amdgcn_s_barrier(); \
                  asm volatile("" ::: "memory"); } while (0)
#define SB0 __builtin_amdgcn_sched_barrier(0)
#define LGK0 asm volatile("s_waitcnt lgkmcnt(0)" ::: "memory")
#define VMW6 asm volatile("s_waitcnt vmcnt(6)" ::: "memory")
#define VMW0 asm volatile("s_waitcnt vmcnt(0)" ::: "memory")

// LDS slot byte offsets
#define b0A0 0
#define b0A1 16384
#define b0B0 32768
#define b0B1 49152
#define b1A0 65536
#define b1A1 81920
#define b1B0 98304
#define b1B1 114688

#define STG(Mp, ld, row0, kt, off)                                                 \
  do {                                                                             \
    load_lds16(Mp + (long)((row0) + w * 8 + srow) * (ld) + (kt) * 64 + scol,       \
               sm + (off) + w * 1024);                                             \
    load_lds16(Mp + (long)((row0) + 64 + w * 8 + srow) * (ld) + (kt) * 64 + scol,  \
               sm + (off) + 8192 + w * 1024);                                      \
  } while (0)

#define RDA32(off)                                                                 \
  _Pragma("unroll") for (int th = 0; th < 2; ++th)                                 \
  _Pragma("unroll") for (int k2 = 0; k2 < 4; ++k2)                                 \
    fa[th][k2] = *(const bf16x8*)(sm + (off) + arowb[th] + kin2[k2]);

#define RDB32(off, dst)                                                            \
  _Pragma("unroll") for (int k2 = 0; k2 < 4; ++k2)                                 \
    dst[k2] = *(const bf16x8*)(sm + (off) + browb + kin2[k2]);

// 16 MFMAs of 32x32x16 per phase; per-acc dep distance 4 (k2 chain)
#define MMQ32(qa)                                                                  \
  __builtin_amdgcn_s_setprio(1);                                                   \
  _Pragma("unroll") for (int k2 = 0; k2 < 4; ++k2)                                 \
  _Pragma("unroll") for (int th = 0; th < 2; ++th) {                               \
    acc[qa][0][th] = __builtin_amdgcn_mfma_f32_32x32x16_bf16(                      \
        fa[th][k2], fb0[k2], acc[qa][0][th], 0, 0, 0);                             \
    acc[qa][1][th] = __builtin_amdgcn_mfma_f32_32x32x16_bf16(                      \
        fa[th][k2], fb1[k2], acc[qa][1][th], 0, 0, 0);                             \
  }                                                                                \
  __builtin_amdgcn_s_setprio(0);

template <int OUT_BF16, int BIAS_MODE, int KSPLIT>   // BIAS: 0 none, 1 col(split@2048), 2 row
__global__ __launch_bounds__(512, 2) void gemm256(
    const u16* __restrict__ A0p, const u16* __restrict__ B0p, void* __restrict__ D0p,
    const float* __restrict__ ba0, const float* __restrict__ bb0,
    const u16* __restrict__ A1p, const u16* __restrict__ B1p, void* __restrict__ D1p,
    const float* __restrict__ ba1, const float* __restrict__ bb1,
    long sKH, int zsplit, int K, int lda, int ldb, int ldd,
    long sA, long sB, long sD) {
  __shared__ __attribute__((aligned(128))) char sm[131072];
  // XCD-chunked swizzle (T1): bijective since nwg % 8 == 0 for all our launches.
  const int gx = gridDim.x, gy = gridDim.y;
  const int nwg = gx * gy * (int)gridDim.z;
  const int lin = blockIdx.x + gx * (blockIdx.y + gy * blockIdx.z);
  const int qch = nwg >> 3;
  int swzid = (lin & 7) * qch + (lin >> 3);
  const int bx = swzid % gx; swzid /= gx;
  const int by = swzid % gy;
  int zb = swzid / gy;
  int kh = 0;
  if (KSPLIT) { kh = zb >> 3; zb &= 7; }
  const bool s1 = (zb >= zsplit);
  const int zz = s1 ? zb - zsplit : zb;
  const u16* Ag = (s1 ? A1p : A0p) + (long)zz * sA + (long)kh * K;
  const u16* Bg = (s1 ? B1p : B0p) + (long)zz * sB + (long)kh * K;
  char* Dg = (char*)(s1 ? D1p : D0p) + (long)zz * sD * (OUT_BF16 ? 2 : 4)
           + (KSPLIT ? (long)kh * sKH : 0L);
  const float* ba = s1 ? ba1 : ba0;
  const float* bb = s1 ? bb1 : bb0;
  const int m0 = by * 256, n0 = bx * 256;
  const int t = threadIdx.x, w = t >> 6, l = t & 63;
  const int wr = w >> 2, wc = w & 3;             // 2x4 waves within a quadrant
  const int lm5 = l & 31, lhi5 = l >> 5;         // 32x32 fragment coords
  const int srow = l >> 3;
  const int scol = ((l & 7) ^ srow) << 3;        // inverse-swizzled source col (elems)
  int arowb[2], kin2[4];
#pragma unroll
  for (int th = 0; th < 2; ++th) arowb[th] = (wr * 64 + th * 32 + lm5) * 128;
  const int browb = (wc * 32 + lm5) * 128;
#pragma unroll
  for (int k2 = 0; k2 < 4; ++k2) kin2[k2] = ((k2 * 2 + lhi5) ^ (l & 7)) << 4;

  f32x16 acc[2][2][2] = {};
  bf16x8 fa[2][4], fb0[4], fb1[4];

  const int nt = K >> 6;                         // K-tiles of 64 (even for all our K)

  // prologue: buf0 full + b1A0,b1B0,b1B1; force buf0 (8 oldest), keep 6 in flight
  STG(Ag, lda, m0,       0, b0A0);
  STG(Bg, ldb, n0,       0, b0B0);
  STG(Bg, ldb, n0 + 128, 0, b0B1);
  STG(Ag, lda, m0 + 128, 0, b0A1);
  STG(Ag, lda, m0,       1, b1A0);
  STG(Bg, ldb, n0,       1, b1B0);
  STG(Bg, ldb, n0 + 128, 1, b1B1);
  VMW6;
  BAR_;

  for (int v = 0; v < nt; v += 2) {
    const int t2 = (v + 2 < nt) ? v + 2 : nt - 1;   // clamped (redundant tail restage ok)
    const int t3 = (v + 3 < nt) ? v + 3 : nt - 1;
    // P0v: tile v, quadrant-row 0
    STG(Ag, lda, m0 + 128, v + 1, b1A1);            // completes buf1 (read @P1w)
    RDA32(b0A0); RDB32(b0B0, fb0); RDB32(b0B1, fb1);
    BAR_; LGK0; SB0; MMQ32(0);
    // P1v: tile v, quadrant-row 1 (fb0/fb1 persist); gate forces b1A1 + older
    STG(Ag, lda, m0, t2, b0A0);
    STG(Bg, ldb, n0, t2, b0B0);
    STG(Bg, ldb, n0 + 128, t2, b0B1);
    RDA32(b0A1);
    VMW6;
    BAR_; LGK0; SB0; MMQ32(1);
    // P0w: tile v+1, quadrant-row 0
    STG(Ag, lda, m0 + 128, t2, b0A1);
    RDA32(b1A0); RDB32(b1B0, fb0); RDB32(b1B1, fb1);
    BAR_; LGK0; SB0; MMQ32(0);
    // P1w: tile v+1, quadrant-row 1; gate forces b0A1(t2) + older
    STG(Ag, lda, m0, t3, b1A0);
    STG(Bg, ldb, n0, t3, b1B0);
    STG(Bg, ldb, n0 + 128, t3, b1B1);
    RDA32(b1A1);
    VMW6;
    BAR_; LGK0; SB0; MMQ32(1);
  }

  // ---------- epilogue: LDS-bounce -> full-line coalesced stores (4 chunks [64][256]) ---
  VMW0;                                          // drain tail stages (land in sm)
  const int esz = OUT_BF16 ? 2 : 4;
#pragma unroll
  for (int qa = 0; qa < 2; ++qa)
#pragma unroll
    for (int th = 0; th < 2; ++th) {
      BAR_;                                      // prev chunk's reads complete
      // write phase: 32x32 C/D fragment layout -> LDS chunk [64 rows][256 cols]
#pragma unroll
      for (int qb = 0; qb < 2; ++qb) {
        const int colb = qb * 128 + wc * 32 + lm5;
        const f32x16 vv = acc[qa][qb][th];
#pragma unroll
        for (int rg = 0; rg < 16; ++rg) {
          const int r32 = (rg & 3) + 8 * (rg >> 2) + 4 * lhi5;
          const int cr = wr * 32 + r32;          // chunk row 0..63
          float x = vv[rg];
          if (BIAS_MODE == 1) {
            const int gc = n0 + colb;
            x += (gc < 2048) ? ba[gc] : bb[gc - 2048];
          }
          if (BIAS_MODE == 2)
            x += ba[m0 + qa * 128 + wr * 64 + th * 32 + r32];
          if (OUT_BF16) ((u16*)sm)[cr * 256 + colb] = f2bf(x);
          else          ((float*)sm)[cr * 256 + colb] = x;
        }
      }
      LGK0;
      BAR_;
      // read-back linear + 16 B/lane dense stores (wave = 1 KB contiguous per instr)
#pragma unroll
      for (int p = 0; p < (OUT_BF16 ? 4 : 8); ++p) {
        const int off = p * 8192 + t * 16;
        const int r = OUT_BF16 ? (off >> 9) : (off >> 10);
        const int inrow = OUT_BF16 ? (off & 511) : (off & 1023);
        const int grow = m0 + qa * 128 + (r >> 5) * 64 + th * 32 + (r & 31);
        const f32x4 d = *(const f32x4*)(sm + off);
        *(f32x4*)(Dg + ((long)grow * ldd + n0) * esz + inrow) = d;
      }
    }
}

// ---------- row softmax over bf16 S0+S1: softmax(alpha*(s0+s1)) -> P bf16 ----------
__global__ void softmax_rows2(const u16* __restrict__ S0, const u16* __restrict__ S1,
                              u16* __restrict__ P, float alpha) {
  const long row = blockIdx.x;
  const int t = threadIdx.x, l = t & 63, w = t >> 6;
  ushort4 a = ((const ushort4*)(S0 + row * 1024))[t];
  ushort4 b = ((const ushort4*)(S1 + row * 1024))[t];
  float v0 = bf2f(a.x) + bf2f(b.x);
  float v1 = bf2f(a.y) + bf2f(b.y);
  float v2 = bf2f(a.z) + bf2f(b.z);
  float v3 = bf2f(a.w) + bf2f(b.w);
  __shared__ float red[8];
  float m = fmaxf(fmaxf(v0, v1), fmaxf(v2, v3));
#pragma unroll
  for (int off = 32; off; off >>= 1) m = fmaxf(m, __shfl_xor(m, off));
  if (l == 0) red[w] = m;
  __syncthreads();
  m = fmaxf(fmaxf(red[0], red[1]), fmaxf(red[2], red[3]));
  float e0 = __expf((v0 - m) * alpha);
  float e1 = __expf((v1 - m) * alpha);
  float e2 = __expf((v2 - m) * alpha);
  float e3 = __expf((v3 - m) * alpha);
  float s = e0 + e1 + e2 + e3;
#pragma unroll
  for (int off = 32; off; off >>= 1) s += __shfl_xor(s, off);
  if (l == 0) red[4 + w] = s;
  __syncthreads();
  s = red[4] + red[5] + red[6] + red[7];
  const float inv = 1.0f / s;
  ushort4 o;
  o.x = f2bf(e0 * inv); o.y = f2bf(e1 * inv);
  o.z = f2bf(e2 * inv); o.w = f2bf(e3 * inv);
  ((ushort4*)(P + row * 1024))[t] = o;
}

// ---------- F_final = AW[b][0] + AW[b][1] ----------
__global__ void final_add(const float4* __restrict__ aw, float4* __restrict__ dst) {
  const long i = (long)blockIdx.x * 256 + threadIdx.x;  // 2,097,152 quads
  const long b = i >> 19;
  const long r = i & 524287;
  float4 a = aw[b * 1048576 + r];
  float4 c = aw[b * 1048576 + 524288 + r];
  float4 o;
  o.x = a.x + c.x; o.y = a.y + c.y; o.z = a.z + c.z; o.w = a.w + c.w;
  dst[i] = o;
}

// ---------- launch ----------
extern "C" void kernel_launch(void* const* d_in, const int* in_sizes, int n_in,
                              void* d_out, int out_size, void* d_ws, size_t ws_size,
                              hipStream_t stream) {
  (void)in_sizes; (void)n_in; (void)out_size; (void)ws_size;
  const float* F_rgb = (const float*)d_in[0];
  const float* F_ind = (const float*)d_in[1];
  const float* bq_rgb = (const float*)d_in[3];
  const float* bk_rgb = (const float*)d_in[5];
  const float* bv_rgb = (const float*)d_in[7];
  const float* bq_ind = (const float*)d_in[9];
  const float* bk_ind = (const float*)d_in[11];
  const float* bv_ind = (const float*)d_in[13];

  char* ws = (char*)d_ws;
  u16* FT_rgb  = (u16*)(ws);                        // [4][1024][2048] bf16
  u16* FT_ind  = (u16*)(ws + 16777216);
  u16* S1c     = (u16*)(ws);                        // ALIAS: K-half-1 scores (FT dead then)
  u16* Wall    = (u16*)(ws + 33554432);             // 6x [2048][2048] bf16
  u16* Wqk_rgb = Wall;                              // [4096][2048] = Wq_rgb | Wk_rgb
  u16* Wqk_ind = (u16*)(ws + 50331648);
  u16* Wv_rgb  = (u16*)(ws + 67108864);
  u16* Wv_ind  = (u16*)(ws + 75497472);
  u16* QKT_rgb = (u16*)(ws + 83886080);             // [4][1024][4096]  Q|K
  u16* QKT_ind = (u16*)(ws + 117440512);
  u16* V_rgb   = (u16*)(ws + 150994944);            // [4][2048][1024]
  u16* V_ind   = (u16*)(ws + 167772160);
  u16* S0c     = (u16*)(ws + 184549376);            // [2][4][1024][1024] bf16
  u16* P       = (u16*)(ws + 218103808);            // [2][4][1024][1024] bf16

  float* out       = (float*)d_out;
  float* out_final = out;                           // [4][2048][1024]
  float* out_Frgb  = out + 8388608;
  float* out_Find  = out + 16777216;
  float* AW        = out + 25165824;                // [4][2][2048][1024]

  // 1) prep: transpose+convert inputs (+identity passthrough) AND weight conversion
  prep<<<dim3(32, 32, 32), dim3(32, 8), 0, stream>>>(
      F_rgb, F_ind, FT_rgb, FT_ind, out_Frgb, out_Find,
      (const float*)d_in[2], (const float*)d_in[4],
      (const float*)d_in[8], (const float*)d_in[10],
      (const float*)d_in[6], (const float*)d_in[12], Wall);

  // 2) fused Q|K convs, both inputs in ONE 512-WG launch (col bias, split@2048)
  gemm256<1, 1, 0><<<dim3(16, 4, 8), 512, 0, stream>>>(
      FT_rgb, Wqk_rgb, QKT_rgb, bq_rgb, bk_rgb,
      FT_ind, Wqk_ind, QKT_ind, bq_ind, bk_ind,
      0L, 4, 2048, 2048, 2048, 4096, 2097152L, 0L, 4194304L);

  // 3) V convs (both inputs): V[c][n] = sum_k Wv[c][k] FT[n][k] + b[c]  (row bias)
  gemm256<1, 2, 0><<<dim3(4, 8, 8), 512, 0, stream>>>(
      Wv_rgb, FT_rgb, V_rgb, bv_rgb, bv_rgb,
      Wv_ind, FT_ind, V_ind, bv_ind, bv_ind,
      0L, 4, 2048, 2048, 2048, 1024, 0L, 2097152L, 2097152L);

  // 4) scores split-K x2 -> bf16 S0 (kh=0) / S1 (kh=1), no atomics
  gemm256<1, 0, 1><<<dim3(4, 4, 16), 512, 0, stream>>>(
      QKT_rgb, QKT_ind + 2048, S0c, nullptr, nullptr,
      QKT_ind, QKT_rgb + 2048, S0c + 4194304, nullptr, nullptr,
      (long)((char*)S1c - (char*)S0c), 4, 1024, 4096, 4096, 1024,
      4194304L, 4194304L, 1048576L);

  // 5) softmax over S0+S1 (scale 1/sqrt(2048) folded in)
  softmax_rows2<<<8192, 256, 0, stream>>>(S0c, S1c, P, 0.02209708691207961f);

  // 6) PV (both directions): AW[c][n] = sum_m V[c][m] P[n][m]  (f32 stores)
  gemm256<0, 0, 0><<<dim3(4, 8, 8), 512, 0, stream>>>(
      V_ind, P, AW, nullptr, nullptr,
      V_rgb, P + 4194304, AW + 2097152, nullptr, nullptr,
      0L, 4, 1024, 1024, 1024, 1024, 2097152L, 1048576L, 4194304L);

  // 7) F_final = AW0 + AW1
  final_add<<<8192, 256, 0, stream>>>((const float4*)AW, (float4*)out_final);
}

// Round 17
// 321.126 us; speedup vs baseline: 1.1553x; 1.1553x over previous
//
#include <hip/hip_runtime.h>

typedef __bf16 bf16x8 __attribute__((ext_vector_type(8)));
typedef float  f32x4  __attribute__((ext_vector_type(4)));
typedef unsigned short u16;
typedef unsigned short u16x8 __attribute__((ext_vector_type(8)));

__device__ __forceinline__ u16 f2bf(float f) {
  unsigned u = __builtin_bit_cast(unsigned, f);
  u += 0x7fffu + ((u >> 16) & 1u);           // round-to-nearest-even
  return (u16)(u >> 16);
}
__device__ __forceinline__ float bf2f(u16 h) {
  return __builtin_bit_cast(float, (unsigned)h << 16);
}

using gvoid = __attribute__((address_space(1))) void;
using svoid = __attribute__((address_space(3))) void;
__device__ __forceinline__ void load_lds16(const void* g, void* s) {
  __builtin_amdgcn_global_load_lds((const gvoid*)g, (svoid*)s, 16, 0, 0);
}

// ---------- prep: transpose+cvt F (z<8, fused passthrough) | weights f32->bf16 (z>=8) ----
__global__ void prep(const float* __restrict__ Fr, const float* __restrict__ Fi,
                     u16* __restrict__ FTr, u16* __restrict__ FTi,
                     float* __restrict__ Or, float* __restrict__ Oi,
                     const float* __restrict__ s0, const float* __restrict__ s1,
                     const float* __restrict__ s2, const float* __restrict__ s3,
                     const float* __restrict__ s4, const float* __restrict__ s5,
                     u16* __restrict__ Wall) {
  const int tx = threadIdx.x, ty = threadIdx.y;
  const int t2 = ty * 32 + tx;
  if (blockIdx.z >= 8) {
    const int gi = (blockIdx.z - 8) * 1024 + blockIdx.y * 32 + blockIdx.x;
    const int chunk = gi >> 12;                         // 6 chunks x 4096 blocks
    const int i = (gi & 4095) * 256 + t2;               // quad index in chunk
    const float* src;
    switch (chunk) {
      case 0: src = s0; break; case 1: src = s1; break; case 2: src = s2; break;
      case 3: src = s3; break; case 4: src = s4; break; default: src = s5; break;
    }
    float4 v = ((const float4*)src)[i];
    ushort4 o;
    o.x = f2bf(v.x); o.y = f2bf(v.y); o.z = f2bf(v.z); o.w = f2bf(v.w);
    ((ushort4*)(Wall + (long)chunk * 4194304))[i] = o;
    return;
  }
  __shared__ float tile[64][33];
  const int b = blockIdx.z & 3;
  const bool ind = (blockIdx.z >= 4);
  const float* F = ind ? Fi : Fr;
  u16* FT = ind ? FTi : FTr;
  float* O = ind ? Oi : Or;
  const int n0 = blockIdx.x * 32, c0 = blockIdx.y * 64;
  const long boff = (long)b * 2048 * 1024;
  const float* Fb = F + boff;
  float* Ob = O + boff;
  u16* FTb = FT + (long)b * 1024 * 2048;
#pragma unroll
  for (int i = 0; i < 8; ++i) {
    const long idx = (long)(c0 + ty + i * 8) * 1024 + n0 + tx;
    float v = Fb[idx];
    tile[ty + i * 8][tx] = v;
    Ob[idx] = v;                                  // identity passthrough (full lines)
  }
  __syncthreads();
  const int q = t2 & 7, r = t2 >> 3;
  u16x8 o8;
#pragma unroll
  for (int k = 0; k < 8; ++k) o8[k] = f2bf(tile[8 * q + k][r]);
  *(u16x8*)(FTb + (long)(n0 + r) * 2048 + c0 + 8 * q) = o8;
}

// ========== shared GEMM machinery (R15-exact core) ==========
#define BAR_ do { asm volatile("" ::: "memory"); __builtin_amdgcn_s_barrier(); \
                  asm volatile("" ::: "memory"); } while (0)
#define SB0 __builtin_amdgcn_sched_barrier(0)
#define LGK0 asm volatile("s_waitcnt lgkmcnt(0)" ::: "memory")
#define VMW6 asm volatile("s_waitcnt vmcnt(6)" ::: "memory")
#define VMW0 asm volatile("s_waitcnt vmcnt(0)" ::: "memory")

#define b0A0 0
#define b0A1 16384
#define b0B0 32768
#define b0B1 49152
#define b1A0 65536
#define b1A1 81920
#define b1B0 98304
#define b1B1 114688

#define STG(Mp, ld, row0, kt, off)                                                 \
  do {                                                                             \
    load_lds16(Mp + (long)((row0) + w * 8 + srow) * (ld) + (kt) * 64 + scol,       \
               sm + (off) + w * 1024);                                             \
    load_lds16(Mp + (long)((row0) + 64 + w * 8 + srow) * (ld) + (kt) * 64 + scol,  \
               sm + (off) + 8192 + w * 1024);                                      \
  } while (0)

#define RDA(off)                                                                   \
  _Pragma("unroll") for (int fm = 0; fm < 4; ++fm)                                 \
  _Pragma("unroll") for (int ks = 0; ks < 2; ++ks)                                 \
    fa[fm][ks] = *(const bf16x8*)(sm + (off) + aoff[fm] + kin[ks]);

#define RDB(off, dst)                                                              \
  _Pragma("unroll") for (int fn = 0; fn < 2; ++fn)                                 \
  _Pragma("unroll") for (int ks = 0; ks < 2; ++ks)                                 \
    dst[fn][ks] = *(const bf16x8*)(sm + (off) + boff[fn] + kin[ks]);

#define MMQ2(qa)                                                                   \
  __builtin_amdgcn_s_setprio(1);                                                   \
  _Pragma("unroll") for (int ks = 0; ks < 2; ++ks)                                 \
  _Pragma("unroll") for (int fm = 0; fm < 4; ++fm) {                               \
    _Pragma("unroll") for (int fn = 0; fn < 2; ++fn)                               \
      acc[qa][0][fm][fn] = __builtin_amdgcn_mfma_f32_16x16x32_bf16(                \
          fa[fm][ks], fb0[fn][ks], acc[qa][0][fm][fn], 0, 0, 0);                   \
    _Pragma("unroll") for (int fn = 0; fn < 2; ++fn)                               \
      acc[qa][1][fm][fn] = __builtin_amdgcn_mfma_f32_16x16x32_bf16(                \
          fa[fm][ks], fb1[fn][ks], acc[qa][1][fm][fn], 0, 0, 0);                   \
  }                                                                                \
  __builtin_amdgcn_s_setprio(0);

// main pipelined loop body over nt K-tiles
#define GEMM_LOOP                                                                  \
  STG(Ag, lda, m0,       0, b0A0);                                                 \
  STG(Bg, ldb, n0,       0, b0B0);                                                 \
  STG(Bg, ldb, n0 + 128, 0, b0B1);                                                 \
  STG(Ag, lda, m0 + 128, 0, b0A1);                                                 \
  STG(Ag, lda, m0,       1, b1A0);                                                 \
  STG(Bg, ldb, n0,       1, b1B0);                                                 \
  STG(Bg, ldb, n0 + 128, 1, b1B1);                                                 \
  VMW6;                                                                            \
  BAR_;                                                                            \
  for (int v = 0; v < nt; v += 2) {                                                \
    const int t2 = (v + 2 < nt) ? v + 2 : nt - 1;                                  \
    const int t3 = (v + 3 < nt) ? v + 3 : nt - 1;                                  \
    STG(Ag, lda, m0 + 128, v + 1, b1A1);                                           \
    RDA(b0A0); RDB(b0B0, fb0); RDB(b0B1, fb1);                                     \
    BAR_; LGK0; SB0; MMQ2(0);                                                      \
    STG(Ag, lda, m0, t2, b0A0);                                                    \
    STG(Bg, ldb, n0, t2, b0B0);                                                    \
    STG(Bg, ldb, n0 + 128, t2, b0B1);                                              \
    RDA(b0A1);                                                                     \
    VMW6;                                                                          \
    BAR_; LGK0; SB0; MMQ2(1);                                                      \
    STG(Ag, lda, m0 + 128, t2, b0A1);                                              \
    RDA(b1A0); RDB(b1B0, fb0); RDB(b1B1, fb1);                                     \
    BAR_; LGK0; SB0; MMQ2(0);                                                      \
    STG(Ag, lda, m0, t3, b1A0);                                                    \
    STG(Bg, ldb, n0, t3, b1B0);                                                    \
    STG(Bg, ldb, n0 + 128, t3, b1B1);                                              \
    RDA(b1A1);                                                                     \
    VMW6;                                                                          \
    BAR_; LGK0; SB0; MMQ2(1);                                                      \
  }

// GEMM thread-geometry locals
#define GEMM_LOCALS                                                                \
  const int t = threadIdx.x, w = t >> 6, l = t & 63;                               \
  const int wr = w >> 2, wc = w & 3;                                               \
  const int lm = l & 15, lk = l >> 4;                                              \
  const int swz = (l & 7) << 4;                                                    \
  const int srow = l >> 3;                                                         \
  const int scol = ((l & 7) ^ srow) << 3;                                          \
  int aoff[4], boff[2], kin[2];                                                    \
  _Pragma("unroll") for (int fm = 0; fm < 4; ++fm)                                 \
    aoff[fm] = (wr * 64 + fm * 16 + lm) * 128;                                     \
  _Pragma("unroll") for (int fn = 0; fn < 2; ++fn)                                 \
    boff[fn] = (wc * 32 + fn * 16 + lm) * 128;                                     \
  kin[0] = (lk * 16) ^ swz;                                                        \
  kin[1] = (64 + lk * 16) ^ swz;                                                   \
  f32x4 acc[2][2][4][2] = {};                                                      \
  bf16x8 fa[4][2], fb0[2][2], fb1[2][2];

// ================= gemm256 (R15-exact): scores + PV =================
template <int OUT_BF16, int BIAS_MODE, int KSPLIT>   // BIAS: 0 none, 1 col(split@2048), 2 row
__global__ __launch_bounds__(512, 2) void gemm256(
    const u16* __restrict__ A0p, const u16* __restrict__ B0p, void* __restrict__ D0p,
    const float* __restrict__ ba0, const float* __restrict__ bb0,
    const u16* __restrict__ A1p, const u16* __restrict__ B1p, void* __restrict__ D1p,
    const float* __restrict__ ba1, const float* __restrict__ bb1,
    long sKH, int zsplit, int K, int lda, int ldb, int ldd,
    long sA, long sB, long sD) {
  __shared__ __attribute__((aligned(128))) char sm[131072];
  const int gx = gridDim.x, gy = gridDim.y;
  const int nwg = gx * gy * (int)gridDim.z;
  const int lin = blockIdx.x + gx * (blockIdx.y + gy * blockIdx.z);
  const int qch = nwg >> 3;
  int swzid = (lin & 7) * qch + (lin >> 3);
  const int bx = swzid % gx; swzid /= gx;
  const int by = swzid % gy;
  int zb = swzid / gy;
  int kh = 0;
  if (KSPLIT) { kh = zb >> 3; zb &= 7; }
  const bool s1 = (zb >= zsplit);
  const int zz = s1 ? zb - zsplit : zb;
  const u16* Ag = (s1 ? A1p : A0p) + (long)zz * sA + (long)kh * K;
  const u16* Bg = (s1 ? B1p : B0p) + (long)zz * sB + (long)kh * K;
  char* Dg = (char*)(s1 ? D1p : D0p) + (long)zz * sD * (OUT_BF16 ? 2 : 4)
           + (KSPLIT ? (long)kh * sKH : 0L);
  const float* ba = s1 ? ba1 : ba0;
  const float* bb = s1 ? bb1 : bb0;
  const int m0 = by * 256, n0 = bx * 256;
  GEMM_LOCALS
  const int nt = K >> 6;

  GEMM_LOOP

  // ---------- epilogue: LDS-bounce -> full-line coalesced stores ----------
  VMW0;
  const int esz = OUT_BF16 ? 2 : 4;
#pragma unroll
  for (int qa = 0; qa < 2; ++qa)
#pragma unroll
    for (int fm = 0; fm < 4; ++fm) {
      BAR_;
#pragma unroll
      for (int qb = 0; qb < 2; ++qb)
#pragma unroll
        for (int fn = 0; fn < 2; ++fn) {
          const int col = qb * 128 + wc * 32 + fn * 16 + lm;
          const f32x4 vv = acc[qa][qb][fm][fn];
#pragma unroll
          for (int j = 0; j < 4; ++j) {
            const int r = wr * 16 + lk * 4 + j;
            float x = vv[j];
            if (BIAS_MODE == 1) {
              const int gc = n0 + col;
              x += (gc < 2048) ? ba[gc] : bb[gc - 2048];
            }
            if (BIAS_MODE == 2)
              x += ba[m0 + qa * 128 + wr * 64 + fm * 16 + lk * 4 + j];
            if (OUT_BF16) ((u16*)sm)[r * 256 + col] = f2bf(x);
            else          ((float*)sm)[r * 256 + col] = x;
          }
        }
      LGK0;
      BAR_;
#pragma unroll
      for (int p = 0; p < (OUT_BF16 ? 2 : 4); ++p) {
        const int off = p * 8192 + t * 16;
        const int r = OUT_BF16 ? (off >> 9) : (off >> 10);
        const int inrow = OUT_BF16 ? (off & 511) : (off & 1023);
        const int grow = m0 + qa * 128 + (r >> 4) * 64 + fm * 16 + (r & 15);
        const f32x4 d = *(const f32x4*)(sm + off);
        *(f32x4*)(Dg + ((long)grow * ldd + n0) * esz + inrow) = d;
      }
    }
}

// ================= gemm_qkv: QK convs (id<512) + V convs (id>=512), one launch =========
// 768 WGs, flat grid. All WGs identical cost (256^2 tile, K=2048, nt=32) -> XCD chunks
// of 96 balanced by construction. QK: D=QKT (col-split bias). V: D=V (row bias).
__global__ __launch_bounds__(512, 2) void gemm_qkv(
    const u16* __restrict__ FT_r, const u16* __restrict__ FT_i,
    const u16* __restrict__ Wqk_r, const u16* __restrict__ Wqk_i,
    const u16* __restrict__ Wv_r, const u16* __restrict__ Wv_i,
    u16* __restrict__ QKT_r, u16* __restrict__ QKT_i,
    u16* __restrict__ V_r, u16* __restrict__ V_i,
    const float* __restrict__ bq_r, const float* __restrict__ bk_r,
    const float* __restrict__ bq_i, const float* __restrict__ bk_i,
    const float* __restrict__ bv_r, const float* __restrict__ bv_i) {
  __shared__ __attribute__((aligned(128))) char sm[131072];
  const int lin = blockIdx.x;                    // 768 WGs; 768 % 8 == 0
  const int id = (lin & 7) * 96 + (lin >> 3);    // XCD-chunked, bijective
  const u16* Ag; const u16* Bg; u16* Dg;
  const float* ba; const float* bb;
  int lda, ldb, ldd, m0, n0, biasmode;
  if (id < 512) {                                // QK set: grid (16,4,8)
    const int bx = id & 15, by = (id >> 4) & 3, zb = id >> 6;
    const bool ind = (zb >= 4);
    const int zz = zb & 3;
    Ag = (ind ? FT_i : FT_r) + (long)zz * 2097152L;
    Bg = ind ? Wqk_i : Wqk_r;
    Dg = (ind ? QKT_i : QKT_r) + (long)zz * 4194304L;
    ba = ind ? bq_i : bq_r;
    bb = ind ? bk_i : bk_r;
    lda = 2048; ldb = 2048; ldd = 4096;
    m0 = by * 256; n0 = bx * 256; biasmode = 1;
  } else {                                       // V set: grid (4,8,8)
    const int id2 = id - 512;
    const int bx = id2 & 3, by = (id2 >> 2) & 7, zb = id2 >> 5;
    const bool ind = (zb >= 4);
    const int zz = zb & 3;
    Ag = ind ? Wv_i : Wv_r;
    Bg = (ind ? FT_i : FT_r) + (long)zz * 2097152L;
    Dg = (ind ? V_i : V_r) + (long)zz * 2097152L;
    ba = ind ? bv_i : bv_r;
    bb = nullptr;
    lda = 2048; ldb = 2048; ldd = 1024;
    m0 = by * 256; n0 = bx * 256; biasmode = 2;
  }
  GEMM_LOCALS
  const int nt = 32;                             // K = 2048 both sets

  GEMM_LOOP

  // epilogue: LDS-bounce, bf16 out; bias mode is WG-uniform runtime branch
  VMW0;
#pragma unroll
  for (int qa = 0; qa < 2; ++qa)
#pragma unroll
    for (int fm = 0; fm < 4; ++fm) {
      BAR_;
#pragma unroll
      for (int qb = 0; qb < 2; ++qb)
#pragma unroll
        for (int fn = 0; fn < 2; ++fn) {
          const int col = qb * 128 + wc * 32 + fn * 16 + lm;
          const f32x4 vv = acc[qa][qb][fm][fn];
#pragma unroll
          for (int j = 0; j < 4; ++j) {
            const int r = wr * 16 + lk * 4 + j;
            float x = vv[j];
            if (biasmode == 1) {
              const int gc = n0 + col;
              x += (gc < 2048) ? ba[gc] : bb[gc - 2048];
            } else {
              x += ba[m0 + qa * 128 + wr * 64 + fm * 16 + lk * 4 + j];
            }
            ((u16*)sm)[r * 256 + col] = f2bf(x);
          }
        }
      LGK0;
      BAR_;
#pragma unroll
      for (int p = 0; p < 2; ++p) {
        const int off = p * 8192 + t * 16;
        const int r = off >> 9;
        const int inrow = off & 511;
        const int grow = m0 + qa * 128 + (r >> 4) * 64 + fm * 16 + (r & 15);
        const f32x4 d = *(const f32x4*)(sm + off);
        *(f32x4*)((char*)Dg + ((long)grow * ldd + n0) * 2 + inrow) = d;
      }
    }
}

// ---------- row softmax over bf16 S0+S1: softmax(alpha*(s0+s1)) -> P bf16 ----------
__global__ void softmax_rows2(const u16* __restrict__ S0, const u16* __restrict__ S1,
                              u16* __restrict__ P, float alpha) {
  const long row = blockIdx.x;
  const int t = threadIdx.x, l = t & 63, w = t >> 6;
  ushort4 a = ((const ushort4*)(S0 + row * 1024))[t];
  ushort4 b = ((const ushort4*)(S1 + row * 1024))[t];
  float v0 = bf2f(a.x) + bf2f(b.x);
  float v1 = bf2f(a.y) + bf2f(b.y);
  float v2 = bf2f(a.z) + bf2f(b.z);
  float v3 = bf2f(a.w) + bf2f(b.w);
  __shared__ float red[8];
  float m = fmaxf(fmaxf(v0, v1), fmaxf(v2, v3));
#pragma unroll
  for (int off = 32; off; off >>= 1) m = fmaxf(m, __shfl_xor(m, off));
  if (l == 0) red[w] = m;
  __syncthreads();
  m = fmaxf(fmaxf(red[0], red[1]), fmaxf(red[2], red[3]));
  float e0 = __expf((v0 - m) * alpha);
  float e1 = __expf((v1 - m) * alpha);
  float e2 = __expf((v2 - m) * alpha);
  float e3 = __expf((v3 - m) * alpha);
  float s = e0 + e1 + e2 + e3;
#pragma unroll
  for (int off = 32; off; off >>= 1) s += __shfl_xor(s, off);
  if (l == 0) red[4 + w] = s;
  __syncthreads();
  s = red[4] + red[5] + red[6] + red[7];
  const float inv = 1.0f / s;
  ushort4 o;
  o.x = f2bf(e0 * inv); o.y = f2bf(e1 * inv);
  o.z = f2bf(e2 * inv); o.w = f2bf(e3 * inv);
  ((ushort4*)(P + row * 1024))[t] = o;
}

// ---------- F_final = AW[b][0] + AW[b][1] ----------
__global__ void final_add(const float4* __restrict__ aw, float4* __restrict__ dst) {
  const long i = (long)blockIdx.x * 256 + threadIdx.x;  // 2,097,152 quads
  const long b = i >> 19;
  const long r = i & 524287;
  float4 a = aw[b * 1048576 + r];
  float4 c = aw[b * 1048576 + 524288 + r];
  float4 o;
  o.x = a.x + c.x; o.y = a.y + c.y; o.z = a.z + c.z; o.w = a.w + c.w;
  dst[i] = o;
}

// ---------- launch ----------
extern "C" void kernel_launch(void* const* d_in, const int* in_sizes, int n_in,
                              void* d_out, int out_size, void* d_ws, size_t ws_size,
                              hipStream_t stream) {
  (void)in_sizes; (void)n_in; (void)out_size; (void)ws_size;
  const float* F_rgb = (const float*)d_in[0];
  const float* F_ind = (const float*)d_in[1];
  const float* bq_rgb = (const float*)d_in[3];
  const float* bk_rgb = (const float*)d_in[5];
  const float* bv_rgb = (const float*)d_in[7];
  const float* bq_ind = (const float*)d_in[9];
  const float* bk_ind = (const float*)d_in[11];
  const float* bv_ind = (const float*)d_in[13];

  char* ws = (char*)d_ws;
  u16* FT_rgb  = (u16*)(ws);                        // [4][1024][2048] bf16
  u16* FT_ind  = (u16*)(ws + 16777216);
  u16* S1c     = (u16*)(ws);                        // ALIAS: K-half-1 scores (FT dead then)
  u16* Wall    = (u16*)(ws + 33554432);             // 6x [2048][2048] bf16
  u16* Wqk_rgb = Wall;                              // [4096][2048] = Wq_rgb | Wk_rgb
  u16* Wqk_ind = (u16*)(ws + 50331648);
  u16* Wv_rgb  = (u16*)(ws + 67108864);
  u16* Wv_ind  = (u16*)(ws + 75497472);
  u16* QKT_rgb = (u16*)(ws + 83886080);             // [4][1024][4096]  Q|K
  u16* QKT_ind = (u16*)(ws + 117440512);
  u16* V_rgb   = (u16*)(ws + 150994944);            // [4][2048][1024]
  u16* V_ind   = (u16*)(ws + 167772160);
  u16* S0c     = (u16*)(ws + 184549376);            // [2][4][1024][1024] bf16
  u16* P       = (u16*)(ws + 218103808);            // [2][4][1024][1024] bf16

  float* out       = (float*)d_out;
  float* out_final = out;                           // [4][2048][1024]
  float* out_Frgb  = out + 8388608;
  float* out_Find  = out + 16777216;
  float* AW        = out + 25165824;                // [4][2][2048][1024]

  // 1) prep: transpose+convert inputs (+identity passthrough) AND weight conversion
  prep<<<dim3(32, 32, 32), dim3(32, 8), 0, stream>>>(
      F_rgb, F_ind, FT_rgb, FT_ind, out_Frgb, out_Find,
      (const float*)d_in[2], (const float*)d_in[4],
      (const float*)d_in[8], (const float*)d_in[10],
      (const float*)d_in[6], (const float*)d_in[12], Wall);

  // 2) QK convs + V convs in ONE 768-WG launch (independent; equal-cost WGs)
  gemm_qkv<<<768, 512, 0, stream>>>(
      FT_rgb, FT_ind, Wqk_rgb, Wqk_ind, Wv_rgb, Wv_ind,
      QKT_rgb, QKT_ind, V_rgb, V_ind,
      bq_rgb, bk_rgb, bq_ind, bk_ind, bv_rgb, bv_ind);

  // 3) scores split-K x2 -> bf16 S0 (kh=0) / S1 (kh=1), no atomics
  gemm256<1, 0, 1><<<dim3(4, 4, 16), 512, 0, stream>>>(
      QKT_rgb, QKT_ind + 2048, S0c, nullptr, nullptr,
      QKT_ind, QKT_rgb + 2048, S0c + 4194304, nullptr, nullptr,
      (long)((char*)S1c - (char*)S0c), 4, 1024, 4096, 4096, 1024,
      4194304L, 4194304L, 1048576L);

  // 4) softmax over S0+S1 (scale 1/sqrt(2048) folded in)
  softmax_rows2<<<8192, 256, 0, stream>>>(S0c, S1c, P, 0.02209708691207961f);

  // 5) PV (both directions): AW[c][n] = sum_m V[c][m] P[n][m]  (f32 stores)
  gemm256<0, 0, 0><<<dim3(4, 8, 8), 512, 0, stream>>>(
      V_ind, P, AW, nullptr, nullptr,
      V_rgb, P + 4194304, AW + 2097152, nullptr, nullptr,
      0L, 4, 1024, 1024, 1024, 1024, 2097152L, 1048576L, 4194304L);

  // 6) F_final = AW0 + AW1
  final_add<<<8192, 256, 0, stream>>>((const float4*)AW, (float4*)out_final);
}